// Round 10
// baseline (784.838 us; speedup 1.0000x reference)
//
#include <hip/hip_runtime.h>

#define S     512
#define NOBS  1024
#define TT    512
#define CH_V  4      // valid chains per workgroup (MFMA N=16: 4 valid + 12 duplicate cols)
#define NWAVE 8
#define NJT   4      // j-tiles (16 rows) per wave: 8*4 = 32 tiles = 512 rows
#define NGRP  16

typedef __attribute__((ext_vector_type(4))) float f32x4;
typedef __attribute__((ext_vector_type(4))) int   i32x4;
typedef __attribute__((ext_vector_type(8))) int   i32x8;
typedef __attribute__((ext_vector_type(2))) unsigned int u32x2;
typedef long i64;

__device__ __forceinline__ unsigned short f2bf(float x) {
  unsigned u = __builtin_bit_cast(unsigned, x);
  return (unsigned short)((u + 0x7fffu + ((u >> 16) & 1u)) >> 16);  // RNE
}
__device__ __forceinline__ float bflo(unsigned u) {       // bf16 low half -> f32
  return __builtin_bit_cast(float, u << 16);
}
__device__ __forceinline__ float bfhi_raw(unsigned u) {   // bf16 high half, low-mantissa garbage (<=2^-7 rel)
  return __builtin_bit_cast(float, u);
}
__device__ __forceinline__ float bfhi(unsigned u) {
  return __builtin_bit_cast(float, u & 0xffff0000u);
}

__device__ __forceinline__ unsigned char f2fp8_sw(float x) {
  x = fminf(fmaxf(x, 0.f), 448.f);
  unsigned u = __builtin_bit_cast(unsigned, x);
  int ex = (int)((u >> 23) & 0xff);
  if (ex >= 121) {
    unsigned m = (u & 0x7fffff) | 0x800000;
    unsigned keep = m >> 20, rest = m & 0xfffff;
    keep += (rest > 0x80000u) || (rest == 0x80000u && (keep & 1));
    int e8 = ex - 127 + 7;
    if (keep == 16) { keep = 8; e8++; }
    if (e8 >= 16) return 0x7e;
    return (unsigned char)((e8 << 3) | (keep & 7));
  } else {
    int m = (int)(x * 512.0f + 0.5f);
    if (m > 8) m = 8;
    return (unsigned char)m;
  }
}

__device__ __forceinline__ unsigned pack4_fp8(float p0, float p1, float p2, float p3) {
#if __has_builtin(__builtin_amdgcn_cvt_pk_fp8_f32)
  int v = __builtin_amdgcn_cvt_pk_fp8_f32(p0, p1, 0, false);
  v = __builtin_amdgcn_cvt_pk_fp8_f32(p2, p3, v, true);
  return (unsigned)v;
#else
  return (unsigned)f2fp8_sw(p0) | ((unsigned)f2fp8_sw(p1) << 8) |
         ((unsigned)f2fp8_sw(p2) << 16) | ((unsigned)f2fp8_sw(p3) << 24);
#endif
}

__device__ __forceinline__ float wave_max(float v) {
  for (int d = 32; d; d >>= 1) v = fmaxf(v, __shfl_xor(v, d));
  return v;
}
__device__ __forceinline__ float wave_sum(float v) {
  for (int d = 32; d; d >>= 1) v += __shfl_xor(v, d);
  return v;
}

// ---- log_pi log-softmax ----
__global__ void prep_pi(const float* __restrict__ log_pi, float* __restrict__ lpi) {
  const int l = threadIdx.x;
  float v[8];
  float mx = -INFINITY;
  for (int k = 0; k < 8; ++k) { v[k] = log_pi[l + 64 * k]; mx = fmaxf(mx, v[k]); }
  mx = wave_max(mx);
  float sm = 0.f;
  for (int k = 0; k < 8; ++k) sm += __expf(v[k] - mx);
  sm = wave_sum(sm);
  const float lse = mx + __logf(sm);
  for (int k = 0; k < 8; ++k) lpi[l + 64 * k] = v[k] - lse;
}

// ---- log_B row log-softmax -> bf16 transposed: Bexp16[o*S + j] ----
__global__ void prep_B(const float* __restrict__ log_B, unsigned short* __restrict__ Bexp16) {
  const int j = blockIdx.x, l = threadIdx.x;
  const float* row = log_B + (size_t)j * NOBS;
  float v[16];
  float mx = -INFINITY;
  for (int k = 0; k < 16; ++k) { v[k] = row[l + 64 * k]; mx = fmaxf(mx, v[k]); }
  mx = wave_max(mx);
  float sm = 0.f;
  for (int k = 0; k < 16; ++k) sm += __expf(v[k] - mx);
  sm = wave_sum(sm);
  const float lse = mx + __logf(sm);
  for (int k = 0; k < 16; ++k) Bexp16[(size_t)(l + 64 * k) * S + j] = f2bf(__expf(v[k] - lse));
}

// ---- log_A row log-softmax -> fp8 e4m3, K=128-chunk fragment order ----
// Afrag8[ ((jt*4 + c)*64 + lane)*32 + e ] = Aexp[i = c*128 + (lane>>4)*32 + e][j = jt*16 + (lane&15)]
__global__ void prep_A(const float* __restrict__ log_A, unsigned char* __restrict__ Afrag8) {
  const int i = blockIdx.x, l = threadIdx.x;
  const float* row = log_A + (size_t)i * S;
  float v[8];
  float mx = -INFINITY;
  for (int k = 0; k < 8; ++k) { v[k] = row[l + 64 * k]; mx = fmaxf(mx, v[k]); }
  mx = wave_max(mx);
  float sm = 0.f;
  for (int k = 0; k < 8; ++k) sm += __expf(v[k] - mx);
  sm = wave_sum(sm);
  const float lse = mx + __logf(sm);
  const int c = i >> 7, g4s = (i >> 5) & 3, e = i & 31;
  for (int k = 0; k < 8; ++k) {
    const int j = l + 64 * k;
    const int jt = j >> 4, jc = j & 15;
    Afrag8[((size_t)(jt * 4 + c) * 64 + g4s * 16 + jc) * 32 + e] = f2fp8_sw(__expf(v[k] - lse));
  }
}

// P LDS swizzle (within one 2 KB buffer): row m (chain 0..3), 16B granule g
__device__ __forceinline__ int pswz(int m, int g) { return m * 512 + (((g ^ m) & 31) << 4); }

__device__ __forceinline__ float max8(const float* p) {
  const f32x4 p0 = *reinterpret_cast<const f32x4*>(p);
  const f32x4 p1 = *reinterpret_cast<const f32x4*>(p + 4);
  return fmaxf(fmaxf(fmaxf(p0[0], p0[1]), fmaxf(p0[2], p0[3])),
               fmaxf(fmaxf(p1[0], p1[1]), fmaxf(p1[2], p1[3])));
}
__device__ __forceinline__ float sum8(const float* p) {
  const f32x4 p0 = *reinterpret_cast<const f32x4*>(p);
  const f32x4 p1 = *reinterpret_cast<const f32x4*>(p + 4);
  return ((p0[0] + p0[1]) + (p0[2] + p0[3])) + ((p1[0] + p1[1]) + (p1[2] + p1[3]));
}

// one K=128 chunk MFMA (scale = 1.0)
__device__ __forceinline__ f32x4 mfma_chunk(const i32x8 a, const i32x8 b, f32x4 acc) {
#if __has_builtin(__builtin_amdgcn_mfma_scale_f32_16x16x128_f8f6f4)
  return __builtin_amdgcn_mfma_scale_f32_16x16x128_f8f6f4(
             a, b, acc, 0, 0, 0, 0x7f7f7f7f, 0, 0x7f7f7f7f);
#else
  const i64* pa = reinterpret_cast<const i64*>(&a);
  const i64* pb = reinterpret_cast<const i64*>(&b);
  #pragma unroll
  for (int q = 0; q < 4; ++q)
    acc = __builtin_amdgcn_mfma_f32_16x16x32_fp8_fp8(pa[q], pb[q], acc, 0, 0, 0);
  return acc;
#endif
}

// ---- main: 16 WGs x 4 chains; dup MFMA cols read same LDS addrs (broadcast) ----
__global__ __launch_bounds__(512, 2)
void hmm_main(const int* __restrict__ obs, const float* __restrict__ lpi,
              const unsigned short* __restrict__ Bexp16,
              const unsigned char* __restrict__ Afrag8, float* __restrict__ parts)
{
  __shared__ __align__(16) unsigned char Pb[2][CH_V * S];  // 2x2 KB fp8
  __shared__ int obs_s[CH_V][TT + 1];
  __shared__ __align__(16) float pred[2][CH_V][12];

  const int tid = threadIdx.x;
  const int w = tid >> 6, l = tid & 63, g4 = l >> 4;
  const int mm = l & 3;                 // valid-chain id (duplicated 4x across cols)
  const bool wlane = ((l & 15) < CH_V); // this lane owns a real column
  const int grp = blockIdx.x;

  // persistent Aexp fragments, chunk order rotated per wave (compile-time idx)
  i32x8 a_frags[NJT][4];
  #pragma unroll
  for (int ji = 0; ji < NJT; ++ji) {
    const int jt = w + NWAVE * ji;
    #pragma unroll
    for (int cc = 0; cc < 4; ++cc) {
      const int c = (cc + w) & 3;
      a_frags[ji][cc] = *reinterpret_cast<const i32x8*>(
          Afrag8 + ((size_t)(jt * 4 + c) * 64 + l) * 32);
    }
  }

  // hoisted LDS byte offsets; dup lanes share addresses with their valid lane
  int rd[4][2], wr[NJT];
  #pragma unroll
  for (int cc = 0; cc < 4; ++cc) {
    const int g0 = ((cc + w) & 3) * 8 + g4 * 2;
    rd[cc][0] = pswz(mm, g0);
    rd[cc][1] = pswz(mm, g0 + 1);
  }
  #pragma unroll
  for (int ji = 0; ji < NJT; ++ji) wr[ji] = pswz(mm, w + NWAVE * ji) + g4 * 4;

  #pragma unroll
  for (int m = 0; m < CH_V; ++m)
    obs_s[m][tid] = obs[(size_t)(grp * CH_V + m) * TT + tid];
  __syncthreads();

  float lsc_f;      // exact log contributions (t0, t1)
  int   lsc_i = 0;  // sum of applied integer log2 scales
  float Lp, e1p;    // predictor state (log2 domain)

  // ---------------- t = 0 (log domain, exact) ----------------
  {
    const int o0 = obs_s[mm][0];
    f32x4 vals[NJT];
    #pragma unroll
    for (int ji = 0; ji < NJT; ++ji) {
      const int j0 = (w + NWAVE * ji) * 16 + g4 * 4;
      const f32x4 lp = *reinterpret_cast<const f32x4*>(lpi + j0);
      const u32x2 e = *reinterpret_cast<const u32x2*>(Bexp16 + (size_t)o0 * S + j0);
      vals[ji][0] = lp[0] + __logf(bflo(e[0]));
      vals[ji][1] = lp[1] + __logf(bfhi(e[0]));
      vals[ji][2] = lp[2] + __logf(bflo(e[1]));
      vals[ji][3] = lp[3] + __logf(bfhi(e[1]));
    }
    float v = -INFINITY;
    #pragma unroll
    for (int ji = 0; ji < NJT; ++ji)
      v = fmaxf(v, fmaxf(fmaxf(vals[ji][0], vals[ji][1]), fmaxf(vals[ji][2], vals[ji][3])));
    v = fmaxf(v, __shfl_xor(v, 16));
    v = fmaxf(v, __shfl_xor(v, 32));
    if (g4 == 0 && wlane) pred[0][mm][w] = v;
    __syncthreads();
    const float M0 = max8(&pred[0][mm][0]);
    #pragma unroll
    for (int ji = 0; ji < NJT; ++ji)
      if (wlane)
        *reinterpret_cast<unsigned*>(&Pb[0][wr[ji]]) =
            pack4_fp8(__expf(vals[ji][0] - M0), __expf(vals[ji][1] - M0),
                      __expf(vals[ji][2] - M0), __expf(vals[ji][3] - M0));
    lsc_f = M0;
    __syncthreads();
  }

  // ---------------- t = 1 (linear, exact) ----------------
  {
    const int o1 = obs_s[mm][1];
    u32x2 eb[NJT];
    const unsigned short* bp = Bexp16 + ((size_t)o1 << 9) + g4 * 4 + w * 16;
    #pragma unroll
    for (int ji = 0; ji < NJT; ++ji)
      eb[ji] = *reinterpret_cast<const u32x2*>(bp + ji * 128);

    f32x4 acc[NJT];
    #pragma unroll
    for (int ji = 0; ji < NJT; ++ji) acc[ji] = f32x4{0.f, 0.f, 0.f, 0.f};
    #pragma unroll
    for (int cc = 0; cc < 4; ++cc) {
      i32x8 af;
      i32x4* h = reinterpret_cast<i32x4*>(&af);
      h[0] = *reinterpret_cast<const i32x4*>(&Pb[0][rd[cc][0]]);
      h[1] = *reinterpret_cast<const i32x4*>(&Pb[0][rd[cc][1]]);
      #pragma unroll
      for (int ji = 0; ji < NJT; ++ji)
        acc[ji] = mfma_chunk(a_frags[ji][cc], af, acc[ji]);
    }
    f32x4 vals[NJT];
    #pragma unroll
    for (int ji = 0; ji < NJT; ++ji) {
      vals[ji][0] = acc[ji][0] * bflo(eb[ji][0]);
      vals[ji][1] = acc[ji][1] * bfhi(eb[ji][0]);
      vals[ji][2] = acc[ji][2] * bflo(eb[ji][1]);
      vals[ji][3] = acc[ji][3] * bfhi(eb[ji][1]);
    }
    float v = -INFINITY;
    #pragma unroll
    for (int ji = 0; ji < NJT; ++ji)
      v = fmaxf(v, fmaxf(fmaxf(vals[ji][0], vals[ji][1]), fmaxf(vals[ji][2], vals[ji][3])));
    v = fmaxf(v, __shfl_xor(v, 16));
    v = fmaxf(v, __shfl_xor(v, 32));
    if (g4 == 0 && wlane) pred[1][mm][w] = v;
    __syncthreads();
    const float v1 = max8(&pred[1][mm][0]);
    const float inv = __builtin_amdgcn_rcpf(v1);
    lsc_f += __logf(v1);
    Lp = __log2f(v1); e1p = 0.f;
    #pragma unroll
    for (int ji = 0; ji < NJT; ++ji)
      if (wlane)
        *reinterpret_cast<unsigned*>(&Pb[1][wr[ji]]) =
            pack4_fp8(vals[ji][0] * inv, vals[ji][1] * inv,
                      vals[ji][2] * inv, vals[ji][3] * inv);
    __syncthreads();
  }

  // ---------------- steady: t = 2 .. 510, one barrier per step ----------------
  for (int t = 2; t < TT - 1; ++t) {
    const int cur = t & 1;
    const unsigned char* __restrict__ pprv = Pb[cur ^ 1];
    unsigned char* __restrict__ pcur = Pb[cur];

    // emission loads first (L2 latency hides under MFMA chain)
    const int ob = obs_s[mm][t];
    u32x2 eb[NJT];
    const unsigned short* bp = Bexp16 + ((size_t)ob << 9) + g4 * 4 + w * 16;
    #pragma unroll
    for (int ji = 0; ji < NJT; ++ji)
      eb[ji] = *reinterpret_cast<const u32x2*>(bp + ji * 128);

    // prev-step cross-wave max (predictor input; consumed only in epilogue)
    const float pm = max8(&pred[cur ^ 1][mm][0]);

    // chunk-interleaved: 2x ds_read_b128 (broadcast across dup cols) then 4 MFMAs
    f32x4 acc[NJT];
    #pragma unroll
    for (int ji = 0; ji < NJT; ++ji) acc[ji] = f32x4{0.f, 0.f, 0.f, 0.f};
    #pragma unroll
    for (int cc = 0; cc < 4; ++cc) {
      i32x8 af;
      i32x4* h = reinterpret_cast<i32x4*>(&af);
      h[0] = *reinterpret_cast<const i32x4*>(pprv + rd[cc][0]);
      h[1] = *reinterpret_cast<const i32x4*>(pprv + rd[cc][1]);
      #pragma unroll
      for (int ji = 0; ji < NJT; ++ji)
        acc[ji] = mfma_chunk(a_frags[ji][cc], af, acc[ji]);
    }

    // integer-log2 predicted scale (post-MFMA application)
    const float e_new = (t == 2) ? 0.f : __log2f(pm);
    const float dsr = fminf(fmaxf(e_new - e1p, -3.0f), 3.0f);
    int s = (int)__builtin_rintf(Lp + e_new + dsr);
    s = min(max(s, -60), 60);
    Lp = (float)s; e1p = e_new; lsc_i += s;
    const float pw2 = __builtin_bit_cast(float, (unsigned)(127 - s) << 23);

    float vmax = 0.f;
    #pragma unroll
    for (int ji = 0; ji < NJT; ++ji) {
      const float q0 = acc[ji][0] * (bflo(eb[ji][0]) * pw2);
      const float q1 = acc[ji][1] * (bfhi_raw(eb[ji][0]) * pw2);
      const float q2 = acc[ji][2] * (bflo(eb[ji][1]) * pw2);
      const float q3 = acc[ji][3] * (bfhi_raw(eb[ji][1]) * pw2);
      if (wlane)
        *reinterpret_cast<unsigned*>(pcur + wr[ji]) = pack4_fp8(q0, q1, q2, q3);
      vmax = fmaxf(fmaxf(vmax, fmaxf(fmaxf(q0, q1), q2)), q3);
    }
    vmax = fmaxf(vmax, __shfl_xor(vmax, 16));
    vmax = fmaxf(vmax, __shfl_xor(vmax, 32));
    if (g4 == 0 && wlane) pred[cur][mm][w] = vmax;
    __syncthreads();
  }

  // ---------------- t = 511 (final: sum) ----------------
  {
    const int t = TT - 1, cur = t & 1;
    const unsigned char* __restrict__ pprv = Pb[cur ^ 1];
    const int ob = obs_s[mm][t];
    u32x2 eb[NJT];
    const unsigned short* bp = Bexp16 + ((size_t)ob << 9) + g4 * 4 + w * 16;
    #pragma unroll
    for (int ji = 0; ji < NJT; ++ji)
      eb[ji] = *reinterpret_cast<const u32x2*>(bp + ji * 128);
    const float pm = max8(&pred[cur ^ 1][mm][0]);

    f32x4 acc[NJT];
    #pragma unroll
    for (int ji = 0; ji < NJT; ++ji) acc[ji] = f32x4{0.f, 0.f, 0.f, 0.f};
    #pragma unroll
    for (int cc = 0; cc < 4; ++cc) {
      i32x8 af;
      i32x4* h = reinterpret_cast<i32x4*>(&af);
      h[0] = *reinterpret_cast<const i32x4*>(pprv + rd[cc][0]);
      h[1] = *reinterpret_cast<const i32x4*>(pprv + rd[cc][1]);
      #pragma unroll
      for (int ji = 0; ji < NJT; ++ji)
        acc[ji] = mfma_chunk(a_frags[ji][cc], af, acc[ji]);
    }

    const float e_new = __log2f(pm);
    const float dsr = fminf(fmaxf(e_new - e1p, -3.0f), 3.0f);
    int s = (int)__builtin_rintf(Lp + e_new + dsr);
    s = min(max(s, -60), 60);
    lsc_i += s;
    const float pw2 = __builtin_bit_cast(float, (unsigned)(127 - s) << 23);

    float ssum = 0.f;
    #pragma unroll
    for (int ji = 0; ji < NJT; ++ji)
      ssum += acc[ji][0] * bflo(eb[ji][0]) + acc[ji][1] * bfhi(eb[ji][0]) +
              acc[ji][2] * bflo(eb[ji][1]) + acc[ji][3] * bfhi(eb[ji][1]);
    ssum *= pw2;
    ssum += __shfl_xor(ssum, 16);
    ssum += __shfl_xor(ssum, 32);
    if (g4 == 0 && wlane) pred[cur][mm][w] = ssum;
    __syncthreads();
    if (w == 0 && g4 == 0 && wlane) {
      const float s8 = sum8(&pred[cur][mm][0]);
      float cl = lsc_f + (float)lsc_i * 0.69314718056f + __logf(s8);
      for (int d = 1; d < CH_V; d <<= 1) cl += __shfl_xor(cl, d);
      if (l == 0) parts[grp] = cl;
    }
  }
}

__global__ void final_sum(const float* __restrict__ parts, float* __restrict__ out) {
  float s = 0.f;
  for (int i = 0; i < NGRP; ++i) s += parts[i];
  out[0] = s;
}

extern "C" void kernel_launch(void* const* d_in, const int* in_sizes, int n_in,
                              void* d_out, int out_size, void* d_ws, size_t ws_size,
                              hipStream_t stream) {
  const int*   obs  = (const int*)d_in[0];
  const float* lgpi = (const float*)d_in[1];
  const float* lgA  = (const float*)d_in[2];
  const float* lgB  = (const float*)d_in[3];
  float* out = (float*)d_out;

  char* ws = (char*)d_ws;
  unsigned short* Bexp16 = (unsigned short*)ws;                          // 1 MB
  unsigned char*  Afrag8 = (unsigned char*)(ws + (size_t)NOBS * S * 2);  // 256 KB
  float*          lpi    = (float*)(ws + (size_t)NOBS * S * 2 + (size_t)S * S);
  float*          parts  = lpi + S;

  prep_pi<<<1, 64, 0, stream>>>(lgpi, lpi);
  prep_B<<<S, 64, 0, stream>>>(lgB, Bexp16);
  prep_A<<<S, 64, 0, stream>>>(lgA, Afrag8);
  hmm_main<<<NGRP, 512, 0, stream>>>(obs, lpi, Bexp16, Afrag8, parts);
  final_sum<<<1, 1, 0, stream>>>(parts, out);
}

// Round 11
// 702.753 us; speedup vs baseline: 1.1168x; 1.1168x over previous
//
#include <hip/hip_runtime.h>

#define S     512
#define NOBS  1024
#define TT    512
#define CH    16     // chains per workgroup (= MFMA N)
#define NWAVE 8
#define NJT   4      // j-tiles (16 rows) per wave: 8*4 = 32 tiles = 512 rows
#define NGRP  4
#define OBSP  (TT + 17)   // odd stride: obs_s reads conflict-free

typedef __attribute__((ext_vector_type(4))) float f32x4;
typedef __attribute__((ext_vector_type(4))) int   i32x4;
typedef __attribute__((ext_vector_type(8))) int   i32x8;
typedef long i64;

__device__ __forceinline__ unsigned char f2fp8_sw(float x) {
  x = fminf(fmaxf(x, 0.f), 448.f);
  unsigned u = __builtin_bit_cast(unsigned, x);
  int ex = (int)((u >> 23) & 0xff);
  if (ex >= 121) {
    unsigned m = (u & 0x7fffff) | 0x800000;
    unsigned keep = m >> 20, rest = m & 0xfffff;
    keep += (rest > 0x80000u) || (rest == 0x80000u && (keep & 1));
    int e8 = ex - 127 + 7;
    if (keep == 16) { keep = 8; e8++; }
    if (e8 >= 16) return 0x7e;
    return (unsigned char)((e8 << 3) | (keep & 7));
  } else {
    int m = (int)(x * 512.0f + 0.5f);
    if (m > 8) m = 8;
    return (unsigned char)m;
  }
}

__device__ __forceinline__ unsigned pack4_fp8(float p0, float p1, float p2, float p3) {
#if __has_builtin(__builtin_amdgcn_cvt_pk_fp8_f32)
  int v = __builtin_amdgcn_cvt_pk_fp8_f32(p0, p1, 0, false);
  v = __builtin_amdgcn_cvt_pk_fp8_f32(p2, p3, v, true);
  return (unsigned)v;
#else
  return (unsigned)f2fp8_sw(p0) | ((unsigned)f2fp8_sw(p1) << 8) |
         ((unsigned)f2fp8_sw(p2) << 16) | ((unsigned)f2fp8_sw(p3) << 24);
#endif
}

__device__ __forceinline__ float wave_max(float v) {
  for (int d = 32; d; d >>= 1) v = fmaxf(v, __shfl_xor(v, d));
  return v;
}
__device__ __forceinline__ float wave_sum(float v) {
  for (int d = 32; d; d >>= 1) v += __shfl_xor(v, d);
  return v;
}

// ---- log_pi log-softmax ----
__global__ void prep_pi(const float* __restrict__ log_pi, float* __restrict__ lpi) {
  const int l = threadIdx.x;
  float v[8];
  float mx = -INFINITY;
  for (int k = 0; k < 8; ++k) { v[k] = log_pi[l + 64 * k]; mx = fmaxf(mx, v[k]); }
  mx = wave_max(mx);
  float sm = 0.f;
  for (int k = 0; k < 8; ++k) sm += __expf(v[k] - mx);
  sm = wave_sum(sm);
  const float lse = mx + __logf(sm);
  for (int k = 0; k < 8; ++k) lpi[l + 64 * k] = v[k] - lse;
}

// ---- log_B row log-softmax -> f32 transposed: Bexp32[o*S + j] = exp(lB[j][o]) ----
__global__ void prep_B(const float* __restrict__ log_B, float* __restrict__ Bexp32) {
  const int j = blockIdx.x, l = threadIdx.x;
  const float* row = log_B + (size_t)j * NOBS;
  float v[16];
  float mx = -INFINITY;
  for (int k = 0; k < 16; ++k) { v[k] = row[l + 64 * k]; mx = fmaxf(mx, v[k]); }
  mx = wave_max(mx);
  float sm = 0.f;
  for (int k = 0; k < 16; ++k) sm += __expf(v[k] - mx);
  sm = wave_sum(sm);
  const float lse = mx + __logf(sm);
  for (int k = 0; k < 16; ++k) Bexp32[(size_t)(l + 64 * k) * S + j] = __expf(v[k] - lse);
}

// ---- log_A row log-softmax -> fp8 e4m3, K=128-chunk fragment order ----
// Afrag8[ ((jt*4 + c)*64 + lane)*32 + e ] = Aexp[i = c*128 + (lane>>4)*32 + e][j = jt*16 + (lane&15)]
__global__ void prep_A(const float* __restrict__ log_A, unsigned char* __restrict__ Afrag8) {
  const int i = blockIdx.x, l = threadIdx.x;
  const float* row = log_A + (size_t)i * S;
  float v[8];
  float mx = -INFINITY;
  for (int k = 0; k < 8; ++k) { v[k] = row[l + 64 * k]; mx = fmaxf(mx, v[k]); }
  mx = wave_max(mx);
  float sm = 0.f;
  for (int k = 0; k < 8; ++k) sm += __expf(v[k] - mx);
  sm = wave_sum(sm);
  const float lse = mx + __logf(sm);
  const int c = i >> 7, g4s = (i >> 5) & 3, e = i & 31;
  for (int k = 0; k < 8; ++k) {
    const int j = l + 64 * k;
    const int jt = j >> 4, jc = j & 15;
    Afrag8[((size_t)(jt * 4 + c) * 64 + g4s * 16 + jc) * 32 + e] = f2fp8_sw(__expf(v[k] - lse));
  }
}

// P LDS swizzle (within one 8 KB buffer): row m (chain), 16B granule g
__device__ __forceinline__ int pswz(int m, int g) { return m * 512 + (((g ^ m) & 31) << 4); }

__device__ __forceinline__ float max8(const float* p) {
  const f32x4 p0 = *reinterpret_cast<const f32x4*>(p);
  const f32x4 p1 = *reinterpret_cast<const f32x4*>(p + 4);
  return fmaxf(fmaxf(fmaxf(p0[0], p0[1]), fmaxf(p0[2], p0[3])),
               fmaxf(fmaxf(p1[0], p1[1]), fmaxf(p1[2], p1[3])));
}
__device__ __forceinline__ float sum8(const float* p) {
  const f32x4 p0 = *reinterpret_cast<const f32x4*>(p);
  const f32x4 p1 = *reinterpret_cast<const f32x4*>(p + 4);
  return ((p0[0] + p0[1]) + (p0[2] + p0[3])) + ((p1[0] + p1[1]) + (p1[2] + p1[3]));
}

// one K=128 chunk MFMA (scale = 1.0)
__device__ __forceinline__ f32x4 mfma_chunk(const i32x8 a, const i32x8 b, f32x4 acc) {
#if __has_builtin(__builtin_amdgcn_mfma_scale_f32_16x16x128_f8f6f4)
  return __builtin_amdgcn_mfma_scale_f32_16x16x128_f8f6f4(
             a, b, acc, 0, 0, 0, 0x7f7f7f7f, 0, 0x7f7f7f7f);
#else
  const i64* pa = reinterpret_cast<const i64*>(&a);
  const i64* pb = reinterpret_cast<const i64*>(&b);
  #pragma unroll
  for (int q = 0; q < 4; ++q)
    acc = __builtin_amdgcn_mfma_f32_16x16x32_fp8_fp8(pa[q], pb[q], acc, 0, 0, 0);
  return acc;
#endif
}

// ---- main: 8 waves (2/SIMD), chunk-interleaved, rotated chunk phases ----
__global__ __launch_bounds__(512, 2)
void hmm_main(const int* __restrict__ obs, const float* __restrict__ lpi,
              const float* __restrict__ Bexp32,
              const unsigned char* __restrict__ Afrag8, float* __restrict__ parts)
{
  __shared__ __align__(16) unsigned char Pb[2][CH * S];   // 16 KB fp8, double-buffered
  __shared__ int obs_s[CH][OBSP];
  __shared__ __align__(16) float pred[2][CH][12];

  const int tid = threadIdx.x;
  const int w = tid >> 6, l = tid & 63, g4 = l >> 4, mm = l & 15;
  const int grp = blockIdx.x;

  // persistent Aexp fragments, chunk order rotated per wave (compile-time idx)
  i32x8 a_frags[NJT][4];
  #pragma unroll
  for (int ji = 0; ji < NJT; ++ji) {
    const int jt = w + NWAVE * ji;
    #pragma unroll
    for (int cc = 0; cc < 4; ++cc) {
      const int c = (cc + w) & 3;
      a_frags[ji][cc] = *reinterpret_cast<const i32x8*>(
          Afrag8 + ((size_t)(jt * 4 + c) * 64 + l) * 32);
    }
  }

  // hoisted LDS byte offsets (reads rotated like a_frags; writes per tile)
  int rd[4][2], wr[NJT];
  #pragma unroll
  for (int cc = 0; cc < 4; ++cc) {
    const int g0 = ((cc + w) & 3) * 8 + g4 * 2;
    rd[cc][0] = pswz(mm, g0);
    rd[cc][1] = pswz(mm, g0 + 1);
  }
  #pragma unroll
  for (int ji = 0; ji < NJT; ++ji) wr[ji] = pswz(mm, w + NWAVE * ji) + g4 * 4;

  for (int m = 0; m < CH; ++m)
    obs_s[m][tid] = obs[(size_t)(grp * CH + m) * TT + tid];
  __syncthreads();

  float lsc_f;      // exact log contributions (t0, t1)
  int   lsc_i = 0;  // sum of applied integer log2 scales
  float Lp, e1p;    // predictor state (log2 domain)

  // ---------------- t = 0 (log domain, exact) ----------------
  {
    const int o0 = obs_s[mm][0];
    f32x4 vals[NJT];
    #pragma unroll
    for (int ji = 0; ji < NJT; ++ji) {
      const int j0 = (w + NWAVE * ji) * 16 + g4 * 4;
      const f32x4 lp = *reinterpret_cast<const f32x4*>(lpi + j0);
      const f32x4 e = *reinterpret_cast<const f32x4*>(Bexp32 + (size_t)o0 * S + j0);
      vals[ji][0] = lp[0] + __logf(e[0]);
      vals[ji][1] = lp[1] + __logf(e[1]);
      vals[ji][2] = lp[2] + __logf(e[2]);
      vals[ji][3] = lp[3] + __logf(e[3]);
    }
    float v = -INFINITY;
    #pragma unroll
    for (int ji = 0; ji < NJT; ++ji)
      v = fmaxf(v, fmaxf(fmaxf(vals[ji][0], vals[ji][1]), fmaxf(vals[ji][2], vals[ji][3])));
    v = fmaxf(v, __shfl_xor(v, 16));
    v = fmaxf(v, __shfl_xor(v, 32));
    if (g4 == 0) pred[0][mm][w] = v;
    __syncthreads();
    const float M0 = max8(&pred[0][mm][0]);
    #pragma unroll
    for (int ji = 0; ji < NJT; ++ji)
      *reinterpret_cast<unsigned*>(&Pb[0][wr[ji]]) =
          pack4_fp8(__expf(vals[ji][0] - M0), __expf(vals[ji][1] - M0),
                    __expf(vals[ji][2] - M0), __expf(vals[ji][3] - M0));
    lsc_f = M0;
    __syncthreads();
  }

  // ---------------- t = 1 (linear, exact) ----------------
  {
    const int o1 = obs_s[mm][1];
    f32x4 eb[NJT];
    const float* bp = Bexp32 + ((size_t)o1 << 9) + g4 * 4 + w * 16;
    #pragma unroll
    for (int ji = 0; ji < NJT; ++ji)
      eb[ji] = *reinterpret_cast<const f32x4*>(bp + ji * 128);

    f32x4 acc[NJT];
    #pragma unroll
    for (int ji = 0; ji < NJT; ++ji) acc[ji] = f32x4{0.f, 0.f, 0.f, 0.f};
    #pragma unroll
    for (int cc = 0; cc < 4; ++cc) {
      i32x8 af;
      i32x4* h = reinterpret_cast<i32x4*>(&af);
      h[0] = *reinterpret_cast<const i32x4*>(&Pb[0][rd[cc][0]]);
      h[1] = *reinterpret_cast<const i32x4*>(&Pb[0][rd[cc][1]]);
      #pragma unroll
      for (int ji = 0; ji < NJT; ++ji)
        acc[ji] = mfma_chunk(a_frags[ji][cc], af, acc[ji]);
    }
    f32x4 vals[NJT];
    #pragma unroll
    for (int ji = 0; ji < NJT; ++ji) {
      vals[ji][0] = acc[ji][0] * eb[ji][0];
      vals[ji][1] = acc[ji][1] * eb[ji][1];
      vals[ji][2] = acc[ji][2] * eb[ji][2];
      vals[ji][3] = acc[ji][3] * eb[ji][3];
    }
    float v = -INFINITY;
    #pragma unroll
    for (int ji = 0; ji < NJT; ++ji)
      v = fmaxf(v, fmaxf(fmaxf(vals[ji][0], vals[ji][1]), fmaxf(vals[ji][2], vals[ji][3])));
    v = fmaxf(v, __shfl_xor(v, 16));
    v = fmaxf(v, __shfl_xor(v, 32));
    if (g4 == 0) pred[1][mm][w] = v;
    __syncthreads();
    const float v1 = max8(&pred[1][mm][0]);
    const float inv = __builtin_amdgcn_rcpf(v1);
    lsc_f += __logf(v1);
    Lp = __log2f(v1); e1p = 0.f;
    #pragma unroll
    for (int ji = 0; ji < NJT; ++ji)
      *reinterpret_cast<unsigned*>(&Pb[1][wr[ji]]) =
          pack4_fp8(vals[ji][0] * inv, vals[ji][1] * inv,
                    vals[ji][2] * inv, vals[ji][3] * inv);
    __syncthreads();
  }

  // ---------------- steady: t = 2 .. 510, one barrier per step ----------------
  for (int t = 2; t < TT - 1; ++t) {
    const int cur = t & 1;
    const unsigned char* __restrict__ pprv = Pb[cur ^ 1];
    unsigned char* __restrict__ pcur = Pb[cur];

    // emission loads first (L2 latency hides under MFMA chain)
    const int ob = obs_s[mm][t];
    f32x4 eb[NJT];
    const float* bp = Bexp32 + ((size_t)ob << 9) + g4 * 4 + w * 16;
    #pragma unroll
    for (int ji = 0; ji < NJT; ++ji)
      eb[ji] = *reinterpret_cast<const f32x4*>(bp + ji * 128);

    // prev-step cross-wave max + predictor + em pre-multiply (overlaps MFMA chain)
    const float pm = max8(&pred[cur ^ 1][mm][0]);
    const float e_new = (t == 2) ? 0.f : __log2f(pm);
    const float dsr = fminf(fmaxf(e_new - e1p, -3.0f), 3.0f);
    int s = (int)__builtin_rintf(Lp + e_new + dsr);
    s = min(max(s, -60), 60);
    Lp = (float)s; e1p = e_new; lsc_i += s;
    const float pw2 = __builtin_bit_cast(float, (unsigned)(127 - s) << 23);
    f32x4 em[NJT];
    #pragma unroll
    for (int ji = 0; ji < NJT; ++ji) {
      em[ji][0] = eb[ji][0] * pw2; em[ji][1] = eb[ji][1] * pw2;
      em[ji][2] = eb[ji][2] * pw2; em[ji][3] = eb[ji][3] * pw2;
    }

    // chunk-interleaved: 2x ds_read_b128 then 4 MFMAs per chunk
    f32x4 acc[NJT];
    #pragma unroll
    for (int ji = 0; ji < NJT; ++ji) acc[ji] = f32x4{0.f, 0.f, 0.f, 0.f};
    #pragma unroll
    for (int cc = 0; cc < 4; ++cc) {
      i32x8 af;
      i32x4* h = reinterpret_cast<i32x4*>(&af);
      h[0] = *reinterpret_cast<const i32x4*>(pprv + rd[cc][0]);
      h[1] = *reinterpret_cast<const i32x4*>(pprv + rd[cc][1]);
      #pragma unroll
      for (int ji = 0; ji < NJT; ++ji)
        acc[ji] = mfma_chunk(a_frags[ji][cc], af, acc[ji]);
    }

    float vmax = 0.f;
    #pragma unroll
    for (int ji = 0; ji < NJT; ++ji) {
      const float q0 = acc[ji][0] * em[ji][0];
      const float q1 = acc[ji][1] * em[ji][1];
      const float q2 = acc[ji][2] * em[ji][2];
      const float q3 = acc[ji][3] * em[ji][3];
      *reinterpret_cast<unsigned*>(pcur + wr[ji]) = pack4_fp8(q0, q1, q2, q3);
      vmax = fmaxf(fmaxf(vmax, fmaxf(fmaxf(q0, q1), q2)), q3);
    }
    vmax = fmaxf(vmax, __shfl_xor(vmax, 16));
    vmax = fmaxf(vmax, __shfl_xor(vmax, 32));
    if (g4 == 0) pred[cur][mm][w] = vmax;
    __syncthreads();
  }

  // ---------------- t = 511 (final: sum) ----------------
  {
    const int t = TT - 1, cur = t & 1;
    const unsigned char* __restrict__ pprv = Pb[cur ^ 1];
    const int ob = obs_s[mm][t];
    f32x4 eb[NJT];
    const float* bp = Bexp32 + ((size_t)ob << 9) + g4 * 4 + w * 16;
    #pragma unroll
    for (int ji = 0; ji < NJT; ++ji)
      eb[ji] = *reinterpret_cast<const f32x4*>(bp + ji * 128);
    const float pm = max8(&pred[cur ^ 1][mm][0]);

    f32x4 acc[NJT];
    #pragma unroll
    for (int ji = 0; ji < NJT; ++ji) acc[ji] = f32x4{0.f, 0.f, 0.f, 0.f};
    #pragma unroll
    for (int cc = 0; cc < 4; ++cc) {
      i32x8 af;
      i32x4* h = reinterpret_cast<i32x4*>(&af);
      h[0] = *reinterpret_cast<const i32x4*>(pprv + rd[cc][0]);
      h[1] = *reinterpret_cast<const i32x4*>(pprv + rd[cc][1]);
      #pragma unroll
      for (int ji = 0; ji < NJT; ++ji)
        acc[ji] = mfma_chunk(a_frags[ji][cc], af, acc[ji]);
    }

    const float e_new = __log2f(pm);
    const float dsr = fminf(fmaxf(e_new - e1p, -3.0f), 3.0f);
    int s = (int)__builtin_rintf(Lp + e_new + dsr);
    s = min(max(s, -60), 60);
    lsc_i += s;
    const float pw2 = __builtin_bit_cast(float, (unsigned)(127 - s) << 23);

    float ssum = 0.f;
    #pragma unroll
    for (int ji = 0; ji < NJT; ++ji)
      ssum += acc[ji][0] * eb[ji][0] + acc[ji][1] * eb[ji][1] +
              acc[ji][2] * eb[ji][2] + acc[ji][3] * eb[ji][3];
    ssum *= pw2;
    ssum += __shfl_xor(ssum, 16);
    ssum += __shfl_xor(ssum, 32);
    if (g4 == 0) pred[cur][mm][w] = ssum;
    __syncthreads();
    if (w == 0 && g4 == 0) {
      const float s8 = sum8(&pred[cur][mm][0]);
      float cl = lsc_f + (float)lsc_i * 0.69314718056f + __logf(s8);
      for (int d = 1; d < 16; d <<= 1) cl += __shfl_xor(cl, d);
      if (l == 0) parts[grp] = cl;
    }
  }
}

__global__ void final_sum(const float* __restrict__ parts, float* __restrict__ out) {
  out[0] = parts[0] + parts[1] + parts[2] + parts[3];
}

extern "C" void kernel_launch(void* const* d_in, const int* in_sizes, int n_in,
                              void* d_out, int out_size, void* d_ws, size_t ws_size,
                              hipStream_t stream) {
  const int*   obs  = (const int*)d_in[0];
  const float* lgpi = (const float*)d_in[1];
  const float* lgA  = (const float*)d_in[2];
  const float* lgB  = (const float*)d_in[3];
  float* out = (float*)d_out;

  char* ws = (char*)d_ws;
  float*          Bexp32 = (float*)ws;                                   // 2 MB
  unsigned char*  Afrag8 = (unsigned char*)(ws + (size_t)NOBS * S * 4);  // 256 KB
  float*          lpi    = (float*)(ws + (size_t)NOBS * S * 4 + (size_t)S * S);
  float*          parts  = lpi + S;

  prep_pi<<<1, 64, 0, stream>>>(lgpi, lpi);
  prep_B<<<S, 64, 0, stream>>>(lgB, Bexp32);
  prep_A<<<S, 64, 0, stream>>>(lgA, Afrag8);
  hmm_main<<<NGRP, 512, 0, stream>>>(obs, lpi, Bexp32, Afrag8, parts);
  final_sum<<<1, 1, 0, stream>>>(parts, out);
}

// Round 12
// 692.898 us; speedup vs baseline: 1.1327x; 1.0142x over previous
//
#include <hip/hip_runtime.h>

#define S     512
#define NOBS  1024
#define TT    512
#define CH    16     // chains per workgroup (= MFMA N)
#define NWAVE 8
#define NJT   4      // j-tiles (16 rows) per wave: 8*4 = 32 tiles = 512 rows
#define NGRP  4
#define OBSP  (TT + 17)

typedef __attribute__((ext_vector_type(4))) float f32x4;
typedef __attribute__((ext_vector_type(4))) int   i32x4;
typedef __attribute__((ext_vector_type(8))) int   i32x8;
typedef long i64;

__device__ __forceinline__ unsigned char f2fp8_sw(float x) {
  x = fminf(fmaxf(x, 0.f), 448.f);
  unsigned u = __builtin_bit_cast(unsigned, x);
  int ex = (int)((u >> 23) & 0xff);
  if (ex >= 121) {
    unsigned m = (u & 0x7fffff) | 0x800000;
    unsigned keep = m >> 20, rest = m & 0xfffff;
    keep += (rest > 0x80000u) || (rest == 0x80000u && (keep & 1));
    int e8 = ex - 127 + 7;
    if (keep == 16) { keep = 8; e8++; }
    if (e8 >= 16) return 0x7e;
    return (unsigned char)((e8 << 3) | (keep & 7));
  } else {
    int m = (int)(x * 512.0f + 0.5f);
    if (m > 8) m = 8;
    return (unsigned char)m;
  }
}

__device__ __forceinline__ unsigned pack4_fp8(float p0, float p1, float p2, float p3) {
#if __has_builtin(__builtin_amdgcn_cvt_pk_fp8_f32)
  int v = __builtin_amdgcn_cvt_pk_fp8_f32(p0, p1, 0, false);
  v = __builtin_amdgcn_cvt_pk_fp8_f32(p2, p3, v, true);
  return (unsigned)v;
#else
  return (unsigned)f2fp8_sw(p0) | ((unsigned)f2fp8_sw(p1) << 8) |
         ((unsigned)f2fp8_sw(p2) << 16) | ((unsigned)f2fp8_sw(p3) << 24);
#endif
}

__device__ __forceinline__ float wave_max(float v) {
  for (int d = 32; d; d >>= 1) v = fmaxf(v, __shfl_xor(v, d));
  return v;
}
__device__ __forceinline__ float wave_sum(float v) {
  for (int d = 32; d; d >>= 1) v += __shfl_xor(v, d);
  return v;
}

// ---- log_pi log-softmax ----
__global__ void prep_pi(const float* __restrict__ log_pi, float* __restrict__ lpi) {
  const int l = threadIdx.x;
  float v[8];
  float mx = -INFINITY;
  for (int k = 0; k < 8; ++k) { v[k] = log_pi[l + 64 * k]; mx = fmaxf(mx, v[k]); }
  mx = wave_max(mx);
  float sm = 0.f;
  for (int k = 0; k < 8; ++k) sm += __expf(v[k] - mx);
  sm = wave_sum(sm);
  const float lse = mx + __logf(sm);
  for (int k = 0; k < 8; ++k) lpi[l + 64 * k] = v[k] - lse;
}

// ---- log_B row log-softmax -> f32 transposed: Bexp32[o*S + j] = exp(lB[j][o]) ----
__global__ void prep_B(const float* __restrict__ log_B, float* __restrict__ Bexp32) {
  const int j = blockIdx.x, l = threadIdx.x;
  const float* row = log_B + (size_t)j * NOBS;
  float v[16];
  float mx = -INFINITY;
  for (int k = 0; k < 16; ++k) { v[k] = row[l + 64 * k]; mx = fmaxf(mx, v[k]); }
  mx = wave_max(mx);
  float sm = 0.f;
  for (int k = 0; k < 16; ++k) sm += __expf(v[k] - mx);
  sm = wave_sum(sm);
  const float lse = mx + __logf(sm);
  for (int k = 0; k < 16; ++k) Bexp32[(size_t)(l + 64 * k) * S + j] = __expf(v[k] - lse);
}

// ---- log_A row log-softmax -> fp8 e4m3, K=128-chunk fragment order ----
__global__ void prep_A(const float* __restrict__ log_A, unsigned char* __restrict__ Afrag8) {
  const int i = blockIdx.x, l = threadIdx.x;
  const float* row = log_A + (size_t)i * S;
  float v[8];
  float mx = -INFINITY;
  for (int k = 0; k < 8; ++k) { v[k] = row[l + 64 * k]; mx = fmaxf(mx, v[k]); }
  mx = wave_max(mx);
  float sm = 0.f;
  for (int k = 0; k < 8; ++k) sm += __expf(v[k] - mx);
  sm = wave_sum(sm);
  const float lse = mx + __logf(sm);
  const int c = i >> 7, g4s = (i >> 5) & 3, e = i & 31;
  for (int k = 0; k < 8; ++k) {
    const int j = l + 64 * k;
    const int jt = j >> 4, jc = j & 15;
    Afrag8[((size_t)(jt * 4 + c) * 64 + g4s * 16 + jc) * 32 + e] = f2fp8_sw(__expf(v[k] - lse));
  }
}

// P LDS swizzle (within one 8 KB buffer): row m (chain), 16B granule g
__device__ __forceinline__ int pswz(int m, int g) { return m * 512 + (((g ^ m) & 31) << 4); }

__device__ __forceinline__ float max8(const float* p) {
  const f32x4 p0 = *reinterpret_cast<const f32x4*>(p);
  const f32x4 p1 = *reinterpret_cast<const f32x4*>(p + 4);
  return fmaxf(fmaxf(fmaxf(p0[0], p0[1]), fmaxf(p0[2], p0[3])),
               fmaxf(fmaxf(p1[0], p1[1]), fmaxf(p1[2], p1[3])));
}
__device__ __forceinline__ float sum8(const float* p) {
  const f32x4 p0 = *reinterpret_cast<const f32x4*>(p);
  const f32x4 p1 = *reinterpret_cast<const f32x4*>(p + 4);
  return ((p0[0] + p0[1]) + (p0[2] + p0[3])) + ((p1[0] + p1[1]) + (p1[2] + p1[3]));
}

// one K=128 chunk MFMA (scale = 1.0)
__device__ __forceinline__ f32x4 mfma_chunk(const i32x8 a, const i32x8 b, f32x4 acc) {
#if __has_builtin(__builtin_amdgcn_mfma_scale_f32_16x16x128_f8f6f4)
  return __builtin_amdgcn_mfma_scale_f32_16x16x128_f8f6f4(
             a, b, acc, 0, 0, 0, 0x7f7f7f7f, 0, 0x7f7f7f7f);
#else
  const i64* pa = reinterpret_cast<const i64*>(&a);
  const i64* pb = reinterpret_cast<const i64*>(&b);
  #pragma unroll
  for (int q = 0; q < 4; ++q)
    acc = __builtin_amdgcn_mfma_f32_16x16x32_fp8_fp8(pa[q], pb[q], acc, 0, 0, 0);
  return acc;
#endif
}

// epilogue for one tile: q = (acc*eb)*2^-s ; fp8-pack ; LDS write ; vmax update
#define EPI_T(ACC, EB, WROFF) {                                            \
  const float q0 = (ACC[0] * EB[0]) * pw2;                                 \
  const float q1 = (ACC[1] * EB[1]) * pw2;                                 \
  const float q2 = (ACC[2] * EB[2]) * pw2;                                 \
  const float q3 = (ACC[3] * EB[3]) * pw2;                                 \
  *reinterpret_cast<unsigned*>(pcur + (WROFF)) = pack4_fp8(q0, q1, q2, q3);\
  vmax = fmaxf(fmaxf(vmax, fmaxf(q0, q1)), fmaxf(q2, q3));                 \
}

#define LOAD_AF(AF, SRC, CC) {                                             \
  i32x4* h_ = reinterpret_cast<i32x4*>(&AF);                               \
  h_[0] = *reinterpret_cast<const i32x4*>((SRC) + rd[CC][0]);              \
  h_[1] = *reinterpret_cast<const i32x4*>((SRC) + rd[CC][1]);              \
}

// ---- main: 8 waves (2/SIMD), epilogue interleaved between MFMA issues ----
__global__ __launch_bounds__(512, 2)
void hmm_main(const int* __restrict__ obs, const float* __restrict__ lpi,
              const float* __restrict__ Bexp32,
              const unsigned char* __restrict__ Afrag8, float* __restrict__ parts)
{
  __shared__ __align__(16) unsigned char Pb[2][CH * S];   // 16 KB fp8, double-buffered
  __shared__ int obs_s[CH][OBSP];
  __shared__ __align__(16) float pred[2][CH][12];

  const int tid = threadIdx.x;
  const int w = tid >> 6, l = tid & 63, g4 = l >> 4, mm = l & 15;
  const int grp = blockIdx.x;

  // persistent Aexp fragments, chunk order rotated per wave (compile-time idx)
  i32x8 a_frags[NJT][4];
  #pragma unroll
  for (int ji = 0; ji < NJT; ++ji) {
    const int jt = w + NWAVE * ji;
    #pragma unroll
    for (int cc = 0; cc < 4; ++cc) {
      const int c = (cc + w) & 3;
      a_frags[ji][cc] = *reinterpret_cast<const i32x8*>(
          Afrag8 + ((size_t)(jt * 4 + c) * 64 + l) * 32);
    }
  }

  // hoisted LDS byte offsets (reads rotated like a_frags; writes per tile)
  int rd[4][2], wr[NJT];
  #pragma unroll
  for (int cc = 0; cc < 4; ++cc) {
    const int g0 = ((cc + w) & 3) * 8 + g4 * 2;
    rd[cc][0] = pswz(mm, g0);
    rd[cc][1] = pswz(mm, g0 + 1);
  }
  #pragma unroll
  for (int ji = 0; ji < NJT; ++ji) wr[ji] = pswz(mm, w + NWAVE * ji) + g4 * 4;

  for (int m = 0; m < CH; ++m)
    obs_s[m][tid] = obs[(size_t)(grp * CH + m) * TT + tid];
  __syncthreads();

  float lsc_f;      // exact log contributions (t0, t1)
  int   lsc_i = 0;  // sum of applied integer log2 scales
  float Lp, e1p;    // predictor state (log2 domain)

  // ---------------- t = 0 (log domain, exact) ----------------
  {
    const int o0 = obs_s[mm][0];
    f32x4 vals[NJT];
    #pragma unroll
    for (int ji = 0; ji < NJT; ++ji) {
      const int j0 = (w + NWAVE * ji) * 16 + g4 * 4;
      const f32x4 lp = *reinterpret_cast<const f32x4*>(lpi + j0);
      const f32x4 e = *reinterpret_cast<const f32x4*>(Bexp32 + (size_t)o0 * S + j0);
      vals[ji][0] = lp[0] + __logf(e[0]);
      vals[ji][1] = lp[1] + __logf(e[1]);
      vals[ji][2] = lp[2] + __logf(e[2]);
      vals[ji][3] = lp[3] + __logf(e[3]);
    }
    float v = -INFINITY;
    #pragma unroll
    for (int ji = 0; ji < NJT; ++ji)
      v = fmaxf(v, fmaxf(fmaxf(vals[ji][0], vals[ji][1]), fmaxf(vals[ji][2], vals[ji][3])));
    v = fmaxf(v, __shfl_xor(v, 16));
    v = fmaxf(v, __shfl_xor(v, 32));
    if (g4 == 0) pred[0][mm][w] = v;
    __syncthreads();
    const float M0 = max8(&pred[0][mm][0]);
    #pragma unroll
    for (int ji = 0; ji < NJT; ++ji)
      *reinterpret_cast<unsigned*>(&Pb[0][wr[ji]]) =
          pack4_fp8(__expf(vals[ji][0] - M0), __expf(vals[ji][1] - M0),
                    __expf(vals[ji][2] - M0), __expf(vals[ji][3] - M0));
    lsc_f = M0;
    __syncthreads();
  }

  // ---------------- t = 1 (linear, exact) ----------------
  {
    const int o1 = obs_s[mm][1];
    f32x4 eb[NJT];
    const float* bp = Bexp32 + ((size_t)o1 << 9) + g4 * 4 + w * 16;
    #pragma unroll
    for (int ji = 0; ji < NJT; ++ji)
      eb[ji] = *reinterpret_cast<const f32x4*>(bp + ji * 128);

    f32x4 acc[NJT];
    #pragma unroll
    for (int ji = 0; ji < NJT; ++ji) acc[ji] = f32x4{0.f, 0.f, 0.f, 0.f};
    #pragma unroll
    for (int cc = 0; cc < 4; ++cc) {
      i32x8 af;
      LOAD_AF(af, &Pb[0][0], cc);
      #pragma unroll
      for (int ji = 0; ji < NJT; ++ji)
        acc[ji] = mfma_chunk(a_frags[ji][cc], af, acc[ji]);
    }
    f32x4 vals[NJT];
    #pragma unroll
    for (int ji = 0; ji < NJT; ++ji) {
      vals[ji][0] = acc[ji][0] * eb[ji][0];
      vals[ji][1] = acc[ji][1] * eb[ji][1];
      vals[ji][2] = acc[ji][2] * eb[ji][2];
      vals[ji][3] = acc[ji][3] * eb[ji][3];
    }
    float v = -INFINITY;
    #pragma unroll
    for (int ji = 0; ji < NJT; ++ji)
      v = fmaxf(v, fmaxf(fmaxf(vals[ji][0], vals[ji][1]), fmaxf(vals[ji][2], vals[ji][3])));
    v = fmaxf(v, __shfl_xor(v, 16));
    v = fmaxf(v, __shfl_xor(v, 32));
    if (g4 == 0) pred[1][mm][w] = v;
    __syncthreads();
    const float v1 = max8(&pred[1][mm][0]);
    const float inv = __builtin_amdgcn_rcpf(v1);
    lsc_f += __logf(v1);
    Lp = __log2f(v1); e1p = 0.f;
    #pragma unroll
    for (int ji = 0; ji < NJT; ++ji)
      *reinterpret_cast<unsigned*>(&Pb[1][wr[ji]]) =
          pack4_fp8(vals[ji][0] * inv, vals[ji][1] * inv,
                    vals[ji][2] * inv, vals[ji][3] * inv);
    __syncthreads();
  }

  // ---------------- steady: t = 2 .. 510, one barrier per step ----------------
  for (int t = 2; t < TT - 1; ++t) {
    const int cur = t & 1;
    const unsigned char* __restrict__ pprv = Pb[cur ^ 1];
    unsigned char* __restrict__ pcur = Pb[cur];

    // emission loads issue at step head; consumed only in epilogue (latency hidden)
    const int ob = obs_s[mm][t];
    const float* bp = Bexp32 + ((size_t)ob << 9) + g4 * 4 + w * 16;
    const f32x4 eb0 = *reinterpret_cast<const f32x4*>(bp);
    const f32x4 eb1 = *reinterpret_cast<const f32x4*>(bp + 128);
    const f32x4 eb2 = *reinterpret_cast<const f32x4*>(bp + 256);
    const f32x4 eb3 = *reinterpret_cast<const f32x4*>(bp + 384);

    // all P-fragment reads issue up front (counted lgkmcnt covers first use)
    i32x8 af0, af1, af2, af3;
    LOAD_AF(af0, pprv, 0);
    LOAD_AF(af1, pprv, 1);
    LOAD_AF(af2, pprv, 2);
    LOAD_AF(af3, pprv, 3);

    // predictor (LDS pred read hides under af reads; applied only in epilogue)
    const float pm = max8(&pred[cur ^ 1][mm][0]);
    const float e_new = (t == 2) ? 0.f : __log2f(pm);
    const float dsr = fminf(fmaxf(e_new - e1p, -3.0f), 3.0f);
    int s = (int)__builtin_rintf(Lp + e_new + dsr);
    s = min(max(s, -60), 60);
    Lp = (float)s; e1p = e_new; lsc_i += s;
    const float pw2 = __builtin_bit_cast(float, (unsigned)(127 - s) << 23);

    float vmax = 0.f;
    f32x4 acc0, acc1, acc2, acc3;
    const f32x4 z = {0.f, 0.f, 0.f, 0.f};

    // pair A: tiles 0,1 (ji-alternating for ILP)
    acc0 = mfma_chunk(a_frags[0][0], af0, z);
    acc1 = mfma_chunk(a_frags[1][0], af0, z);
    acc0 = mfma_chunk(a_frags[0][1], af1, acc0);
    acc1 = mfma_chunk(a_frags[1][1], af1, acc1);
    acc0 = mfma_chunk(a_frags[0][2], af2, acc0);
    acc1 = mfma_chunk(a_frags[1][2], af2, acc1);
    acc0 = mfma_chunk(a_frags[0][3], af3, acc0);
    acc1 = mfma_chunk(a_frags[1][3], af3, acc1);

    // pair B MFMAs with pair-A epilogues threaded between the issues
    acc2 = mfma_chunk(a_frags[2][0], af0, z);
    acc3 = mfma_chunk(a_frags[3][0], af0, z);
    EPI_T(acc0, eb0, wr[0]);
    acc2 = mfma_chunk(a_frags[2][1], af1, acc2);
    acc3 = mfma_chunk(a_frags[3][1], af1, acc3);
    EPI_T(acc1, eb1, wr[1]);
    acc2 = mfma_chunk(a_frags[2][2], af2, acc2);
    acc3 = mfma_chunk(a_frags[3][2], af2, acc3);
    acc2 = mfma_chunk(a_frags[2][3], af3, acc2);
    acc3 = mfma_chunk(a_frags[3][3], af3, acc3);
    EPI_T(acc2, eb2, wr[2]);
    EPI_T(acc3, eb3, wr[3]);

    vmax = fmaxf(vmax, __shfl_xor(vmax, 16));
    vmax = fmaxf(vmax, __shfl_xor(vmax, 32));
    if (g4 == 0) pred[cur][mm][w] = vmax;
    __syncthreads();
  }

  // ---------------- t = 511 (final: sum) ----------------
  {
    const int t = TT - 1, cur = t & 1;
    const unsigned char* __restrict__ pprv = Pb[cur ^ 1];
    const int ob = obs_s[mm][t];
    f32x4 eb[NJT];
    const float* bp = Bexp32 + ((size_t)ob << 9) + g4 * 4 + w * 16;
    #pragma unroll
    for (int ji = 0; ji < NJT; ++ji)
      eb[ji] = *reinterpret_cast<const f32x4*>(bp + ji * 128);
    const float pm = max8(&pred[cur ^ 1][mm][0]);

    f32x4 acc[NJT];
    #pragma unroll
    for (int ji = 0; ji < NJT; ++ji) acc[ji] = f32x4{0.f, 0.f, 0.f, 0.f};
    #pragma unroll
    for (int cc = 0; cc < 4; ++cc) {
      i32x8 af;
      LOAD_AF(af, pprv, cc);
      #pragma unroll
      for (int ji = 0; ji < NJT; ++ji)
        acc[ji] = mfma_chunk(a_frags[ji][cc], af, acc[ji]);
    }

    const float e_new = __log2f(pm);
    const float dsr = fminf(fmaxf(e_new - e1p, -3.0f), 3.0f);
    int s = (int)__builtin_rintf(Lp + e_new + dsr);
    s = min(max(s, -60), 60);
    lsc_i += s;
    const float pw2 = __builtin_bit_cast(float, (unsigned)(127 - s) << 23);

    float ssum = 0.f;
    #pragma unroll
    for (int ji = 0; ji < NJT; ++ji)
      ssum += acc[ji][0] * eb[ji][0] + acc[ji][1] * eb[ji][1] +
              acc[ji][2] * eb[ji][2] + acc[ji][3] * eb[ji][3];
    ssum *= pw2;
    ssum += __shfl_xor(ssum, 16);
    ssum += __shfl_xor(ssum, 32);
    if (g4 == 0) pred[cur][mm][w] = ssum;
    __syncthreads();
    if (w == 0 && g4 == 0) {
      const float s8 = sum8(&pred[cur][mm][0]);
      float cl = lsc_f + (float)lsc_i * 0.69314718056f + __logf(s8);
      for (int d = 1; d < 16; d <<= 1) cl += __shfl_xor(cl, d);
      if (l == 0) parts[grp] = cl;
    }
  }
}

__global__ void final_sum(const float* __restrict__ parts, float* __restrict__ out) {
  out[0] = parts[0] + parts[1] + parts[2] + parts[3];
}

extern "C" void kernel_launch(void* const* d_in, const int* in_sizes, int n_in,
                              void* d_out, int out_size, void* d_ws, size_t ws_size,
                              hipStream_t stream) {
  const int*   obs  = (const int*)d_in[0];
  const float* lgpi = (const float*)d_in[1];
  const float* lgA  = (const float*)d_in[2];
  const float* lgB  = (const float*)d_in[3];
  float* out = (float*)d_out;

  char* ws = (char*)d_ws;
  float*          Bexp32 = (float*)ws;                                   // 2 MB
  unsigned char*  Afrag8 = (unsigned char*)(ws + (size_t)NOBS * S * 4);  // 256 KB
  float*          lpi    = (float*)(ws + (size_t)NOBS * S * 4 + (size_t)S * S);
  float*          parts  = lpi + S;

  prep_pi<<<1, 64, 0, stream>>>(lgpi, lpi);
  prep_B<<<S, 64, 0, stream>>>(lgB, Bexp32);
  prep_A<<<S, 64, 0, stream>>>(lgA, Afrag8);
  hmm_main<<<NGRP, 512, 0, stream>>>(obs, lpi, Bexp32, Afrag8, parts);
  final_sum<<<1, 1, 0, stream>>>(parts, out);
}